// Round 5
// baseline (267.685 us; speedup 1.0000x reference)
//
#include <hip/hip_runtime.h>

// Block-resident-LDS fused kernel, 16-wave blocks (4 waves/SIMD).
// out[n,k,c] = sigmoid(s[n,256+c]) * sum_pq F[pq,k]*(T@X1)[pq,c]*(T@X2)[pq,c]
//              + (k==0 ? silu(s[n,c])*s[n,128+c] : 0)

#define KC    49
#define PQ    324
#define NPX   12544     // 49*256
#define OUTK  6272      // 49*128
#define NTILE 11
// tiled+padded weights in d_ws, staged whole into LDS per block:
// Tw: [11 tiles][32 pq][72 i]  bf16 (144 B rows -> 4-way b128 conflicts max)
// Fw: [11 tiles][64 k ][40 pq] bf16 (80 B rows)
#define TWROW  72
#define TWTILE 2304     // 32*72
#define TWTOT  25344    // 11*TWTILE
#define FWROW  40
#define FWTILE 2560     // 64*40
#define FWTOT  28160    // 11*FWTILE
#define WTOT   (TWTOT + FWTOT)   // 53504 elems = 107008 B

typedef __attribute__((ext_vector_type(8)))  short bf16x8;
typedef __attribute__((ext_vector_type(16))) float f32x16;
typedef __attribute__((ext_vector_type(4)))  unsigned int u32x4;

__device__ __forceinline__ unsigned int cvtpk_bf16(float lo, float hi) {
    unsigned int r;
    asm("v_cvt_pk_bf16_f32 %0, %1, %2" : "=v"(r) : "v"(lo), "v"(hi));
    return r;
}
__device__ __forceinline__ unsigned short f2bf(float f) {
    unsigned u = __builtin_bit_cast(unsigned, f);
    return (unsigned short)((u + 0x7FFFu + ((u >> 16) & 1u)) >> 16);   // RNE
}

__global__ void prep_kernel(const float* __restrict__ Tg, const float* __restrict__ Fg,
                            unsigned short* __restrict__ W)
{
    const int idx = blockIdx.x * 256 + threadIdx.x;
    if (idx < TWTOT) {
        const int t = idx / TWTILE, rem = idx % TWTILE;
        const int r = rem / TWROW,  i   = rem % TWROW;
        const int pq = 32 * t + r;
        const float v = (i < KC && pq < PQ) ? Tg[pq * KC + i] : 0.0f;
        W[idx] = f2bf(v);
    } else if (idx < WTOT) {
        const int idx2 = idx - TWTOT;
        const int t = idx2 / FWTILE, rem = idx2 % FWTILE;
        const int k = rem / FWROW,   p   = rem % FWROW;
        const int pq = 32 * t + p;
        const float v = (k < KC && p < 32 && pq < PQ) ? Fg[pq * KC + k] : 0.0f;
        W[idx] = f2bf(v);
    }
}

__global__ __launch_bounds__(1024, 4)
void s2_fused(const float* __restrict__ X,            // [N][49][256]
              const float* __restrict__ S,            // [N][384]
              const unsigned short* __restrict__ W,   // tiled Tw+Fw blob
              float* __restrict__ out,                // [N][49][128]
              int nit)                                // n-quads per block
{
    __shared__ __align__(16) unsigned short lds[WTOT];   // 107008 B -> 1 block/CU

    const int tid = threadIdx.x;
    // ---- one-time stage of tiled T/F into LDS ----
    for (int idx = tid; idx < WTOT / 8; idx += 1024) {
        const u32x4 v = *(const u32x4*)(W + (size_t)idx * 8);
        *(u32x4*)(lds + (size_t)idx * 8) = v;
    }
    __syncthreads();   // only barrier; LDS read-only afterwards

    const int w  = tid >> 6;     // wave 0..15
    const int l  = tid & 63;
    const int cl = l & 31;
    const int hb = l >> 5;
    const int cs = w & 3;        // c-slice (c = 32*cs + cl)
    const int nw = w >> 2;       // n-lane 0..3

    const unsigned short* tw = lds;
    const unsigned short* fw = lds + TWTOT;

    const int nbase = blockIdx.x * (4 * nit) + nw;

    float fr[2][4][8];           // raw fp32 X gather (next-n pipeline)
    float sraw0, sraw1, sraw2;

    // ---- prologue gather for first n ----
    {
        const float* xp = X + (size_t)nbase * NPX + 32 * cs + cl;
#pragma unroll
        for (int xi = 0; xi < 2; ++xi)
#pragma unroll
        for (int st = 0; st < 4; ++st)
#pragma unroll
        for (int j = 0; j < 8; ++j) {
            const int i = 16 * st + 8 * hb + j;
            fr[xi][st][j] = (i < KC) ? xp[128 * xi + (size_t)i * 256] : 0.0f;
        }
        const float* sp = S + (size_t)nbase * 384 + 32 * cs + cl;
        sraw0 = sp[0]; sraw1 = sp[128]; sraw2 = sp[256];
    }

    for (int it = 0; it < nit; ++it) {
        const int n = nbase + 4 * it;

        // activations for current n (before sraw is overwritten)
        const float sg  = 1.0f / (1.0f + __expf(-sraw2));
        const float osc = (sraw0 / (1.0f + __expf(-sraw0))) * sraw1;

        // convert current gather to bf16 B-frags
        bf16x8 bx[2][4];
#pragma unroll
        for (int xi = 0; xi < 2; ++xi)
#pragma unroll
        for (int st = 0; st < 4; ++st) {
            u32x4 d;
#pragma unroll
            for (int p = 0; p < 4; ++p)
                d[p] = cvtpk_bf16(fr[xi][st][2 * p], fr[xi][st][2 * p + 1]);
            bx[xi][st] = __builtin_bit_cast(bf16x8, d);
        }

        // ---- prefetch next n's X + scalars (hides under tile loop) ----
        {
            const int n2 = nbase + 4 * ((it + 1 < nit) ? it + 1 : it);
            const float* xp = X + (size_t)n2 * NPX + 32 * cs + cl;
#pragma unroll
            for (int xi = 0; xi < 2; ++xi)
#pragma unroll
            for (int st = 0; st < 4; ++st)
#pragma unroll
            for (int j = 0; j < 8; ++j) {
                const int i = 16 * st + 8 * hb + j;
                fr[xi][st][j] = (i < KC) ? xp[128 * xi + (size_t)i * 256] : 0.0f;
            }
            const float* sp = S + (size_t)n2 * 384 + 32 * cs + cl;
            sraw0 = sp[0]; sraw1 = sp[128]; sraw2 = sp[256];
        }

        f32x16 accO0, accO1, fz;
#pragma unroll
        for (int r = 0; r < 16; ++r) { accO0[r] = 0.0f; accO1[r] = 0.0f; fz[r] = 0.0f; }

#pragma unroll 2
        for (int t = 0; t < NTILE; ++t) {
            // A-frags from LDS
            const unsigned short* twt = tw + t * TWTILE + cl * TWROW + hb * 8;
            const bf16x8 ta0 = *(const bf16x8*)(twt);
            const bf16x8 ta1 = *(const bf16x8*)(twt + 16);
            const bf16x8 ta2 = *(const bf16x8*)(twt + 32);
            const bf16x8 ta3 = *(const bf16x8*)(twt + 48);
            const unsigned short* fwt = fw + t * FWTILE + cl * FWROW + hb * 8;
            const bf16x8 fa00 = *(const bf16x8*)(fwt);
            const bf16x8 fa01 = *(const bf16x8*)(fwt + 16);
            const bf16x8 fa10 = *(const bf16x8*)(fwt + 32 * FWROW);
            const bf16x8 fa11 = *(const bf16x8*)(fwt + 32 * FWROW + 16);

            // GEMM1: 32pq x 32c, K=64 in 4 steps, both halves x1/x2
            f32x16 ac0 = fz, ac1 = fz;
            ac0 = __builtin_amdgcn_mfma_f32_32x32x16_bf16(ta0, bx[0][0], ac0, 0, 0, 0);
            ac1 = __builtin_amdgcn_mfma_f32_32x32x16_bf16(ta0, bx[1][0], ac1, 0, 0, 0);
            ac0 = __builtin_amdgcn_mfma_f32_32x32x16_bf16(ta1, bx[0][1], ac0, 0, 0, 0);
            ac1 = __builtin_amdgcn_mfma_f32_32x32x16_bf16(ta1, bx[1][1], ac1, 0, 0, 0);
            ac0 = __builtin_amdgcn_mfma_f32_32x32x16_bf16(ta2, bx[0][2], ac0, 0, 0, 0);
            ac1 = __builtin_amdgcn_mfma_f32_32x32x16_bf16(ta2, bx[1][2], ac1, 0, 0, 0);
            ac0 = __builtin_amdgcn_mfma_f32_32x32x16_bf16(ta3, bx[0][3], ac0, 0, 0, 0);
            ac1 = __builtin_amdgcn_mfma_f32_32x32x16_bf16(ta3, bx[1][3], ac1, 0, 0, 0);

            // gate + pack to bf16 pairs
            unsigned int q0 = cvtpk_bf16(ac0[0]  * ac1[0],  ac0[1]  * ac1[1]);
            unsigned int q1 = cvtpk_bf16(ac0[2]  * ac1[2],  ac0[3]  * ac1[3]);
            unsigned int q2 = cvtpk_bf16(ac0[4]  * ac1[4],  ac0[5]  * ac1[5]);
            unsigned int q3 = cvtpk_bf16(ac0[6]  * ac1[6],  ac0[7]  * ac1[7]);
            unsigned int q4 = cvtpk_bf16(ac0[8]  * ac1[8],  ac0[9]  * ac1[9]);
            unsigned int q5 = cvtpk_bf16(ac0[10] * ac1[10], ac0[11] * ac1[11]);
            unsigned int q6 = cvtpk_bf16(ac0[12] * ac1[12], ac0[13] * ac1[13]);
            unsigned int q7 = cvtpk_bf16(ac0[14] * ac1[14], ac0[15] * ac1[15]);

            // half-wave exchange: C-layout (4-row groups) -> B-frag layout (8-row groups)
            asm("v_permlane32_swap_b32 %0, %1" : "+v"(q0), "+v"(q2));
            asm("v_permlane32_swap_b32 %0, %1" : "+v"(q1), "+v"(q3));
            asm("v_permlane32_swap_b32 %0, %1" : "+v"(q4), "+v"(q6));
            asm("v_permlane32_swap_b32 %0, %1" : "+v"(q5), "+v"(q7));
            u32x4 b0v, b1v;
            b0v[0] = q0; b0v[1] = q1; b0v[2] = q2; b0v[3] = q3;
            b1v[0] = q4; b1v[1] = q5; b1v[2] = q6; b1v[3] = q7;
            const bf16x8 bg0 = __builtin_bit_cast(bf16x8, b0v);
            const bf16x8 bg1 = __builtin_bit_cast(bf16x8, b1v);

            // GEMM2: out-tiles k 0..31 / 32..63, two K=16 pq-steps
            accO0 = __builtin_amdgcn_mfma_f32_32x32x16_bf16(fa00, bg0, accO0, 0, 0, 0);
            accO1 = __builtin_amdgcn_mfma_f32_32x32x16_bf16(fa10, bg0, accO1, 0, 0, 0);
            accO0 = __builtin_amdgcn_mfma_f32_32x32x16_bf16(fa01, bg1, accO0, 0, 0, 0);
            accO1 = __builtin_amdgcn_mfma_f32_32x32x16_bf16(fa11, bg1, accO1, 0, 0, 0);
        }

        // ---- epilogue: gate, SwiGLU merge at k==0, store ----
        float* op = out + (size_t)n * OUTK + 32 * cs + cl;
#pragma unroll
        for (int r = 0; r < 16; ++r) {
            const int k0 = (r & 3) + 8 * (r >> 2) + 4 * hb;
            float v = sg * accO0[r];
            if (k0 == 0) v += osc;               // only r==0, hb==0
            op[(size_t)k0 * 128] = v;
            const int k1 = 32 + k0;
            if (k1 < KC) op[(size_t)k1 * 128] = sg * accO1[r];
        }
    }
}

extern "C" void kernel_launch(void* const* d_in, const int* in_sizes, int n_in,
                              void* d_out, int out_size, void* d_ws, size_t ws_size,
                              hipStream_t stream) {
    const float* inputs  = (const float*)d_in[0];
    const float* scalars = (const float*)d_in[1];
    const float* Tg      = (const float*)d_in[2];
    const float* Fg      = (const float*)d_in[3];
    float* outp          = (float*)d_out;

    unsigned short* W = (unsigned short*)d_ws;   // WTOT elems = 107008 B

    const int N = in_sizes[1] / 384;             // 4096
    hipLaunchKernelGGL(prep_kernel, dim3((WTOT + 255) / 256), dim3(256), 0, stream,
                       Tg, Fg, W);

    const int nit  = 4;                          // n-quads per block
    const int grid = N / (4 * nit);              // 256 blocks, 16 n each
    hipLaunchKernelGGL(s2_fused, dim3(grid), dim3(1024), 0, stream,
                       inputs, scalars, W, outp, nit);
}

// Round 6
// 266.317 us; speedup vs baseline: 1.0051x; 1.0051x over previous
//
#include <hip/hip_runtime.h>

// Block-resident-LDS fused kernel, 16-wave blocks (4 waves/SIMD), no-spill bounds.
// out[n,k,c] = sigmoid(s[n,256+c]) * sum_pq F[pq,k]*(T@X1)[pq,c]*(T@X2)[pq,c]
//              + (k==0 ? silu(s[n,c])*s[n,128+c] : 0)

#define KC    49
#define PQ    324
#define NPX   12544     // 49*256
#define OUTK  6272      // 49*128
#define NTILE 11
// tiled+padded weights in d_ws, staged whole into LDS per block:
// Tw: [11 tiles][32 pq][72 i]  bf16 (144 B rows -> max 4-way b128 conflicts)
// Fw: [11 tiles][64 k ][40 pq] bf16 (80 B rows)
#define TWROW  72
#define TWTILE 2304     // 32*72
#define TWTOT  25344    // 11*TWTILE
#define FWROW  40
#define FWTILE 2560     // 64*40
#define FWTOT  28160    // 11*FWTILE
#define WTOT   (TWTOT + FWTOT)   // 53504 elems = 107008 B

typedef __attribute__((ext_vector_type(8)))  short bf16x8;
typedef __attribute__((ext_vector_type(16))) float f32x16;
typedef __attribute__((ext_vector_type(4)))  unsigned int u32x4;

__device__ __forceinline__ unsigned int cvtpk_bf16(float lo, float hi) {
    unsigned int r;
    asm("v_cvt_pk_bf16_f32 %0, %1, %2" : "=v"(r) : "v"(lo), "v"(hi));
    return r;
}
__device__ __forceinline__ unsigned short f2bf(float f) {
    unsigned u = __builtin_bit_cast(unsigned, f);
    return (unsigned short)((u + 0x7FFFu + ((u >> 16) & 1u)) >> 16);   // RNE
}

__global__ void prep_kernel(const float* __restrict__ Tg, const float* __restrict__ Fg,
                            unsigned short* __restrict__ W)
{
    const int idx = blockIdx.x * 256 + threadIdx.x;
    if (idx < TWTOT) {
        const int t = idx / TWTILE, rem = idx % TWTILE;
        const int r = rem / TWROW,  i   = rem % TWROW;
        const int pq = 32 * t + r;
        const float v = (i < KC && pq < PQ) ? Tg[pq * KC + i] : 0.0f;
        W[idx] = f2bf(v);
    } else if (idx < WTOT) {
        const int idx2 = idx - TWTOT;
        const int t = idx2 / FWTILE, rem = idx2 % FWTILE;
        const int k = rem / FWROW,   p   = rem % FWROW;
        const int pq = 32 * t + p;
        const float v = (k < KC && p < 32 && pq < PQ) ? Fg[pq * KC + k] : 0.0f;
        W[idx] = f2bf(v);
    }
}

__global__ __launch_bounds__(1024)   // cap = 128 VGPR (16 waves must fit 1 CU); body needs ~120
void s2_fused(const float* __restrict__ X,            // [N][49][256]
              const float* __restrict__ S,            // [N][384]
              const unsigned short* __restrict__ W,   // tiled Tw+Fw blob
              float* __restrict__ out,                // [N][49][128]
              int nit)                                // n-quads per block
{
    __shared__ __align__(16) unsigned short lds[WTOT];   // 107008 B -> 1 block/CU

    const int tid = threadIdx.x;
    // ---- one-time stage of tiled T/F into LDS ----
    for (int idx = tid; idx < WTOT / 8; idx += 1024) {
        const u32x4 v = *(const u32x4*)(W + (size_t)idx * 8);
        *(u32x4*)(lds + (size_t)idx * 8) = v;
    }
    __syncthreads();   // only barrier; LDS read-only afterwards

    const int w  = tid >> 6;     // wave 0..15
    const int l  = tid & 63;
    const int cl = l & 31;
    const int hb = l >> 5;
    const int cs = w & 3;        // c-slice (c = 32*cs + cl)
    const int nw = w >> 2;       // n-lane 0..3

    const unsigned short* tw = lds;
    const unsigned short* fw = lds + TWTOT;

    const int nbase = blockIdx.x * (4 * nit) + nw;

    float fr[2][4][8];           // raw fp32 X gather (next-n pipeline)
    float sraw0, sraw1, sraw2;

    // ---- prologue gather for first n ----
    {
        const float* xp = X + (size_t)nbase * NPX + 32 * cs + cl;
#pragma unroll
        for (int xi = 0; xi < 2; ++xi)
#pragma unroll
        for (int st = 0; st < 4; ++st)
#pragma unroll
        for (int j = 0; j < 8; ++j) {
            const int i = 16 * st + 8 * hb + j;
            fr[xi][st][j] = (i < KC) ? xp[128 * xi + (size_t)i * 256] : 0.0f;
        }
        const float* sp = S + (size_t)nbase * 384 + 32 * cs + cl;
        sraw0 = sp[0]; sraw1 = sp[128]; sraw2 = sp[256];
    }

    for (int it = 0; it < nit; ++it) {
        const int n = nbase + 4 * it;

        // activations for current n (before sraw is overwritten)
        const float sg  = 1.0f / (1.0f + __expf(-sraw2));
        const float osc = (sraw0 / (1.0f + __expf(-sraw0))) * sraw1;

        // convert current gather to bf16 B-frags
        bf16x8 bx[2][4];
#pragma unroll
        for (int xi = 0; xi < 2; ++xi)
#pragma unroll
        for (int st = 0; st < 4; ++st) {
            u32x4 d;
#pragma unroll
            for (int p = 0; p < 4; ++p)
                d[p] = cvtpk_bf16(fr[xi][st][2 * p], fr[xi][st][2 * p + 1]);
            bx[xi][st] = __builtin_bit_cast(bf16x8, d);
        }

        // ---- prefetch next n's X + scalars (hides under tile loop) ----
        {
            const int n2 = nbase + 4 * ((it + 1 < nit) ? it + 1 : it);
            const float* xp = X + (size_t)n2 * NPX + 32 * cs + cl;
#pragma unroll
            for (int xi = 0; xi < 2; ++xi)
#pragma unroll
            for (int st = 0; st < 4; ++st)
#pragma unroll
            for (int j = 0; j < 8; ++j) {
                const int i = 16 * st + 8 * hb + j;
                fr[xi][st][j] = (i < KC) ? xp[128 * xi + (size_t)i * 256] : 0.0f;
            }
            const float* sp = S + (size_t)n2 * 384 + 32 * cs + cl;
            sraw0 = sp[0]; sraw1 = sp[128]; sraw2 = sp[256];
        }

        f32x16 accO0, accO1;
#pragma unroll
        for (int r = 0; r < 16; ++r) { accO0[r] = 0.0f; accO1[r] = 0.0f; }

#pragma unroll 2
        for (int t = 0; t < NTILE; ++t) {
            // A-frags from LDS
            const unsigned short* twt = tw + t * TWTILE + cl * TWROW + hb * 8;
            const bf16x8 ta0 = *(const bf16x8*)(twt);
            const bf16x8 ta1 = *(const bf16x8*)(twt + 16);
            const bf16x8 ta2 = *(const bf16x8*)(twt + 32);
            const bf16x8 ta3 = *(const bf16x8*)(twt + 48);
            const unsigned short* fwt = fw + t * FWTILE + cl * FWROW + hb * 8;
            const bf16x8 fa00 = *(const bf16x8*)(fwt);
            const bf16x8 fa01 = *(const bf16x8*)(fwt + 16);
            const bf16x8 fa10 = *(const bf16x8*)(fwt + 32 * FWROW);
            const bf16x8 fa11 = *(const bf16x8*)(fwt + 32 * FWROW + 16);

            // GEMM1: 32pq x 32c, K=64 in 4 steps, both halves x1/x2
            f32x16 ac0, ac1;
#pragma unroll
            for (int r = 0; r < 16; ++r) { ac0[r] = 0.0f; ac1[r] = 0.0f; }
            ac0 = __builtin_amdgcn_mfma_f32_32x32x16_bf16(ta0, bx[0][0], ac0, 0, 0, 0);
            ac1 = __builtin_amdgcn_mfma_f32_32x32x16_bf16(ta0, bx[1][0], ac1, 0, 0, 0);
            ac0 = __builtin_amdgcn_mfma_f32_32x32x16_bf16(ta1, bx[0][1], ac0, 0, 0, 0);
            ac1 = __builtin_amdgcn_mfma_f32_32x32x16_bf16(ta1, bx[1][1], ac1, 0, 0, 0);
            ac0 = __builtin_amdgcn_mfma_f32_32x32x16_bf16(ta2, bx[0][2], ac0, 0, 0, 0);
            ac1 = __builtin_amdgcn_mfma_f32_32x32x16_bf16(ta2, bx[1][2], ac1, 0, 0, 0);
            ac0 = __builtin_amdgcn_mfma_f32_32x32x16_bf16(ta3, bx[0][3], ac0, 0, 0, 0);
            ac1 = __builtin_amdgcn_mfma_f32_32x32x16_bf16(ta3, bx[1][3], ac1, 0, 0, 0);

            // gate + pack to bf16 pairs
            unsigned int q0 = cvtpk_bf16(ac0[0]  * ac1[0],  ac0[1]  * ac1[1]);
            unsigned int q1 = cvtpk_bf16(ac0[2]  * ac1[2],  ac0[3]  * ac1[3]);
            unsigned int q2 = cvtpk_bf16(ac0[4]  * ac1[4],  ac0[5]  * ac1[5]);
            unsigned int q3 = cvtpk_bf16(ac0[6]  * ac1[6],  ac0[7]  * ac1[7]);
            unsigned int q4 = cvtpk_bf16(ac0[8]  * ac1[8],  ac0[9]  * ac1[9]);
            unsigned int q5 = cvtpk_bf16(ac0[10] * ac1[10], ac0[11] * ac1[11]);
            unsigned int q6 = cvtpk_bf16(ac0[12] * ac1[12], ac0[13] * ac1[13]);
            unsigned int q7 = cvtpk_bf16(ac0[14] * ac1[14], ac0[15] * ac1[15]);

            // half-wave exchange: C-layout (4-row groups) -> B-frag layout (8-row groups)
            asm("v_permlane32_swap_b32 %0, %1" : "+v"(q0), "+v"(q2));
            asm("v_permlane32_swap_b32 %0, %1" : "+v"(q1), "+v"(q3));
            asm("v_permlane32_swap_b32 %0, %1" : "+v"(q4), "+v"(q6));
            asm("v_permlane32_swap_b32 %0, %1" : "+v"(q5), "+v"(q7));
            u32x4 b0v, b1v;
            b0v[0] = q0; b0v[1] = q1; b0v[2] = q2; b0v[3] = q3;
            b1v[0] = q4; b1v[1] = q5; b1v[2] = q6; b1v[3] = q7;
            const bf16x8 bg0 = __builtin_bit_cast(bf16x8, b0v);
            const bf16x8 bg1 = __builtin_bit_cast(bf16x8, b1v);

            // GEMM2: out-tiles k 0..31 / 32..63, two K=16 pq-steps
            accO0 = __builtin_amdgcn_mfma_f32_32x32x16_bf16(fa00, bg0, accO0, 0, 0, 0);
            accO1 = __builtin_amdgcn_mfma_f32_32x32x16_bf16(fa10, bg0, accO1, 0, 0, 0);
            accO0 = __builtin_amdgcn_mfma_f32_32x32x16_bf16(fa01, bg1, accO0, 0, 0, 0);
            accO1 = __builtin_amdgcn_mfma_f32_32x32x16_bf16(fa11, bg1, accO1, 0, 0, 0);
        }

        // ---- epilogue: gate, SwiGLU merge at k==0, store ----
        float* op = out + (size_t)n * OUTK + 32 * cs + cl;
#pragma unroll
        for (int r = 0; r < 16; ++r) {
            const int k0 = (r & 3) + 8 * (r >> 2) + 4 * hb;
            float v = sg * accO0[r];
            if (k0 == 0) v += osc;               // only r==0, hb==0
            op[(size_t)k0 * 128] = v;
            const int k1 = 32 + k0;
            if (k1 < KC) op[(size_t)k1 * 128] = sg * accO1[r];
        }
    }
}

extern "C" void kernel_launch(void* const* d_in, const int* in_sizes, int n_in,
                              void* d_out, int out_size, void* d_ws, size_t ws_size,
                              hipStream_t stream) {
    const float* inputs  = (const float*)d_in[0];
    const float* scalars = (const float*)d_in[1];
    const float* Tg      = (const float*)d_in[2];
    const float* Fg      = (const float*)d_in[3];
    float* outp          = (float*)d_out;

    unsigned short* W = (unsigned short*)d_ws;   // WTOT elems = 107008 B

    const int N = in_sizes[1] / 384;             // 4096
    hipLaunchKernelGGL(prep_kernel, dim3((WTOT + 255) / 256), dim3(256), 0, stream,
                       Tg, Fg, W);

    const int nit  = 4;                          // n-quads per block
    const int grid = N / (4 * nit);              // 256 blocks, 16 n each
    hipLaunchKernelGGL(s2_fused, dim3(grid), dim3(1024), 0, stream,
                       inputs, scalars, W, outp, nit);
}

// Round 7
// 94.482 us; speedup vs baseline: 2.8332x; 2.8187x over previous
//
#include <hip/hip_runtime.h>

// Block-resident-LDS fused kernel. 512-thr blocks, <80KB LDS -> 2 blocks/CU (4 waves/SIMD).
// out[n,k,c] = sigmoid(s[n,256+c]) * sum_pq F[pq,k]*(T@X1)[pq,c]*(T@X2)[pq,c]
//              + (k==0 ? silu(s[n,c])*s[n,128+c] : 0)

#define KC    49
#define PQ    324
#define NPX   12544     // 49*256
#define OUTK  6272      // 49*128
#define NTILE 11
// LDS-resident weights (bf16), minimal padding:
// T[325][68]: row=pq (324 = zero row), col=i (49..67 zero). 136 B rows, b64-aligned.
// F[50][356]: row=k  (49  = zero row), col=pq (324..355 zero). 712 B rows, b64-aligned.
#define TROWS 325
#define TCOLS 68
#define FROWS 50
#define FCOLS 356
#define TTOT  (TROWS * TCOLS)        // 22100
#define FTOT  (FROWS * FCOLS)        // 17800
#define WTOT  (TTOT + FTOT)          // 39900 elems
#define WPAD  39904                  // round to x8 for 16B staging; 79808 B

typedef __attribute__((ext_vector_type(8)))  short bf16x8;
typedef __attribute__((ext_vector_type(4)))  short bf16x4;
typedef __attribute__((ext_vector_type(16))) float f32x16;
typedef __attribute__((ext_vector_type(4)))  unsigned int u32x4;

__device__ __forceinline__ unsigned int cvtpk_bf16(float lo, float hi) {
    unsigned int r;
    asm("v_cvt_pk_bf16_f32 %0, %1, %2" : "=v"(r) : "v"(lo), "v"(hi));
    return r;
}
__device__ __forceinline__ unsigned short f2bf(float f) {
    unsigned u = __builtin_bit_cast(unsigned, f);
    return (unsigned short)((u + 0x7FFFu + ((u >> 16) & 1u)) >> 16);   // RNE
}
// two ds_read_b64 (rows are only 8-B aligned)
__device__ __forceinline__ bf16x8 ld8(const unsigned short* p) {
    const bf16x4 lo = *(const bf16x4*)p;
    const bf16x4 hi = *(const bf16x4*)(p + 4);
    bf16x8 r;
    r[0] = lo[0]; r[1] = lo[1]; r[2] = lo[2]; r[3] = lo[3];
    r[4] = hi[0]; r[5] = hi[1]; r[6] = hi[2]; r[7] = hi[3];
    return r;
}

__global__ void prep_kernel(const float* __restrict__ Tg, const float* __restrict__ Fg,
                            unsigned short* __restrict__ W)
{
    const int idx = blockIdx.x * 256 + threadIdx.x;
    if (idx < TTOT) {
        const int r = idx / TCOLS, i = idx % TCOLS;
        const float v = (r < PQ && i < KC) ? Tg[r * KC + i] : 0.0f;
        W[idx] = f2bf(v);
    } else if (idx < WPAD) {
        float v = 0.0f;
        if (idx < WTOT) {
            const int idx2 = idx - TTOT;
            const int k = idx2 / FCOLS, p = idx2 % FCOLS;
            if (k < KC && p < PQ) v = Fg[p * KC + k];
        }
        W[idx] = f2bf(v);
    }
}

__global__ __launch_bounds__(512, 2)
void s2_fused(const float* __restrict__ X,            // [N][49][256]
              const float* __restrict__ S,            // [N][384]
              const unsigned short* __restrict__ W,   // T/F blob
              float* __restrict__ out,                // [N][49][128]
              int nit)                                // n-pairs per block
{
    __shared__ __align__(16) unsigned short lds[WPAD];   // 79808 B -> 2 blocks/CU

    const int tid = threadIdx.x;
    // ---- one-time stage of T/F into LDS ----
    for (int idx = tid; idx < WPAD / 8; idx += 512) {
        const u32x4 v = *(const u32x4*)(W + (size_t)idx * 8);
        *(u32x4*)(lds + (size_t)idx * 8) = v;
    }
    __syncthreads();   // only barrier; LDS read-only afterwards

    const int w  = tid >> 6;
    const int l  = tid & 63;
    const int cl = l & 31;
    const int hb = l >> 5;
    const int cs = w >> 1;   // c-slice 0..3 (c = 32*cs + cl)
    const int nw = w & 1;    // which n of the pair

    const unsigned short* tw  = lds;
    const unsigned short* fw0 = lds + TTOT + (size_t)cl * FCOLS;                 // k = cl
    const unsigned short* fw1 = lds + TTOT + (size_t)min(cl + 32, KC) * FCOLS;   // k = 32+cl (clamped to zero row)

    const int nbase = blockIdx.x * (2 * nit) + nw;

    float fr[2][4][8];           // raw fp32 X gather (next-n pipeline)
    float sraw0, sraw1, sraw2;

    // ---- prologue gather for first n ----
    {
        const float* xp = X + (size_t)nbase * NPX + 32 * cs + cl;
#pragma unroll
        for (int xi = 0; xi < 2; ++xi)
#pragma unroll
        for (int st = 0; st < 4; ++st)
#pragma unroll
        for (int j = 0; j < 8; ++j) {
            const int i = 16 * st + 8 * hb + j;
            fr[xi][st][j] = (i < KC) ? xp[128 * xi + (size_t)i * 256] : 0.0f;
        }
        const float* sp = S + (size_t)nbase * 384 + 32 * cs + cl;
        sraw0 = sp[0]; sraw1 = sp[128]; sraw2 = sp[256];
    }

    for (int it = 0; it < nit; ++it) {
        const int n = nbase + 2 * it;

        // activations for current n (before sraw is overwritten)
        const float sg  = 1.0f / (1.0f + __expf(-sraw2));
        const float osc = (sraw0 / (1.0f + __expf(-sraw0))) * sraw1;

        // convert current gather to bf16 B-frags
        bf16x8 bx[2][4];
#pragma unroll
        for (int xi = 0; xi < 2; ++xi)
#pragma unroll
        for (int st = 0; st < 4; ++st) {
            u32x4 d;
#pragma unroll
            for (int p = 0; p < 4; ++p)
                d[p] = cvtpk_bf16(fr[xi][st][2 * p], fr[xi][st][2 * p + 1]);
            bx[xi][st] = __builtin_bit_cast(bf16x8, d);
        }

        // ---- prefetch next n's X + scalars (hides under tile loop) ----
        {
            const int n2 = nbase + 2 * ((it + 1 < nit) ? it + 1 : it);
            const float* xp = X + (size_t)n2 * NPX + 32 * cs + cl;
#pragma unroll
            for (int xi = 0; xi < 2; ++xi)
#pragma unroll
            for (int st = 0; st < 4; ++st)
#pragma unroll
            for (int j = 0; j < 8; ++j) {
                const int i = 16 * st + 8 * hb + j;
                fr[xi][st][j] = (i < KC) ? xp[128 * xi + (size_t)i * 256] : 0.0f;
            }
            const float* sp = S + (size_t)n2 * 384 + 32 * cs + cl;
            sraw0 = sp[0]; sraw1 = sp[128]; sraw2 = sp[256];
        }

        f32x16 accO0, accO1;
#pragma unroll
        for (int r = 0; r < 16; ++r) { accO0[r] = 0.0f; accO1[r] = 0.0f; }

#pragma unroll 2
        for (int t = 0; t < NTILE; ++t) {
            // A-frags from LDS (b64 pairs)
            const int trow = min(32 * t + cl, 324);              // clamp only bites at t=10
            const unsigned short* twt = tw + trow * TCOLS + 8 * hb;
            const bf16x8 ta0 = ld8(twt);
            const bf16x8 ta1 = ld8(twt + 16);
            const bf16x8 ta2 = ld8(twt + 32);
            const bf16x8 ta3 = ld8(twt + 48);
            const int fcol = 32 * t + 8 * hb;
            const bf16x8 fa00 = ld8(fw0 + fcol);
            const bf16x8 fa01 = ld8(fw0 + fcol + 16);
            const bf16x8 fa10 = ld8(fw1 + fcol);
            const bf16x8 fa11 = ld8(fw1 + fcol + 16);

            // GEMM1: 32pq x 32c, K=64 in 4 steps, both halves x1/x2
            f32x16 ac0, ac1;
#pragma unroll
            for (int r = 0; r < 16; ++r) { ac0[r] = 0.0f; ac1[r] = 0.0f; }
            ac0 = __builtin_amdgcn_mfma_f32_32x32x16_bf16(ta0, bx[0][0], ac0, 0, 0, 0);
            ac1 = __builtin_amdgcn_mfma_f32_32x32x16_bf16(ta0, bx[1][0], ac1, 0, 0, 0);
            ac0 = __builtin_amdgcn_mfma_f32_32x32x16_bf16(ta1, bx[0][1], ac0, 0, 0, 0);
            ac1 = __builtin_amdgcn_mfma_f32_32x32x16_bf16(ta1, bx[1][1], ac1, 0, 0, 0);
            ac0 = __builtin_amdgcn_mfma_f32_32x32x16_bf16(ta2, bx[0][2], ac0, 0, 0, 0);
            ac1 = __builtin_amdgcn_mfma_f32_32x32x16_bf16(ta2, bx[1][2], ac1, 0, 0, 0);
            ac0 = __builtin_amdgcn_mfma_f32_32x32x16_bf16(ta3, bx[0][3], ac0, 0, 0, 0);
            ac1 = __builtin_amdgcn_mfma_f32_32x32x16_bf16(ta3, bx[1][3], ac1, 0, 0, 0);

            // gate + pack to bf16 pairs
            unsigned int q0 = cvtpk_bf16(ac0[0]  * ac1[0],  ac0[1]  * ac1[1]);
            unsigned int q1 = cvtpk_bf16(ac0[2]  * ac1[2],  ac0[3]  * ac1[3]);
            unsigned int q2 = cvtpk_bf16(ac0[4]  * ac1[4],  ac0[5]  * ac1[5]);
            unsigned int q3 = cvtpk_bf16(ac0[6]  * ac1[6],  ac0[7]  * ac1[7]);
            unsigned int q4 = cvtpk_bf16(ac0[8]  * ac1[8],  ac0[9]  * ac1[9]);
            unsigned int q5 = cvtpk_bf16(ac0[10] * ac1[10], ac0[11] * ac1[11]);
            unsigned int q6 = cvtpk_bf16(ac0[12] * ac1[12], ac0[13] * ac1[13]);
            unsigned int q7 = cvtpk_bf16(ac0[14] * ac1[14], ac0[15] * ac1[15]);

            // half-wave exchange: C-layout (4-row groups) -> B-frag layout (8-row groups)
            asm("v_permlane32_swap_b32 %0, %1" : "+v"(q0), "+v"(q2));
            asm("v_permlane32_swap_b32 %0, %1" : "+v"(q1), "+v"(q3));
            asm("v_permlane32_swap_b32 %0, %1" : "+v"(q4), "+v"(q6));
            asm("v_permlane32_swap_b32 %0, %1" : "+v"(q5), "+v"(q7));
            u32x4 b0v, b1v;
            b0v[0] = q0; b0v[1] = q1; b0v[2] = q2; b0v[3] = q3;
            b1v[0] = q4; b1v[1] = q5; b1v[2] = q6; b1v[3] = q7;
            const bf16x8 bg0 = __builtin_bit_cast(bf16x8, b0v);
            const bf16x8 bg1 = __builtin_bit_cast(bf16x8, b1v);

            // GEMM2: out-tiles k 0..31 / 32..48, two K=16 pq-steps
            accO0 = __builtin_amdgcn_mfma_f32_32x32x16_bf16(fa00, bg0, accO0, 0, 0, 0);
            accO1 = __builtin_amdgcn_mfma_f32_32x32x16_bf16(fa10, bg0, accO1, 0, 0, 0);
            accO0 = __builtin_amdgcn_mfma_f32_32x32x16_bf16(fa01, bg1, accO0, 0, 0, 0);
            accO1 = __builtin_amdgcn_mfma_f32_32x32x16_bf16(fa11, bg1, accO1, 0, 0, 0);
        }

        // ---- epilogue: gate, SwiGLU merge at k==0, store ----
        float* op = out + (size_t)n * OUTK + 32 * cs + cl;
#pragma unroll
        for (int r = 0; r < 16; ++r) {
            const int k0 = (r & 3) + 8 * (r >> 2) + 4 * hb;
            float v = sg * accO0[r];
            if (k0 == 0) v += osc;               // only r==0, hb==0
            op[(size_t)k0 * 128] = v;
            const int k1 = 32 + k0;
            if (k1 < KC) op[(size_t)k1 * 128] = sg * accO1[r];
        }
    }
}

extern "C" void kernel_launch(void* const* d_in, const int* in_sizes, int n_in,
                              void* d_out, int out_size, void* d_ws, size_t ws_size,
                              hipStream_t stream) {
    const float* inputs  = (const float*)d_in[0];
    const float* scalars = (const float*)d_in[1];
    const float* Tg      = (const float*)d_in[2];
    const float* Fg      = (const float*)d_in[3];
    float* outp          = (float*)d_out;

    unsigned short* W = (unsigned short*)d_ws;   // WPAD elems = 79808 B

    const int N = in_sizes[1] / 384;             // 4096
    hipLaunchKernelGGL(prep_kernel, dim3((WPAD + 255) / 256), dim3(256), 0, stream,
                       Tg, Fg, W);

    const int nit  = 4;                          // n-pairs per block
    const int grid = N / (2 * nit);              // 512 blocks -> 2 resident/CU
    hipLaunchKernelGGL(s2_fused, dim3(grid), dim3(512), 0, stream,
                       inputs, scalars, W, outp, nit);
}